// Round 1
// baseline (547.697 us; speedup 1.0000x reference)
//
#include <hip/hip_runtime.h>
#include <math.h>

#define NPOL   1000
#define NTICK  98000
#define NCOMM  1000
#define NN     100000
#define NE     1000000
#define NE2    1100000   // NE + NN self-loops

// ---------------------------------------------------------------------------
// K0: fold edge-attention weights: we1[d][h] = sum_f c1_eW[d][h*16+f]*c1_ae[h][f]
//     we2[d] = sum_f c2_eW[d][f]*c2_ae[f]
__global__ void k_we(const float* __restrict__ c1_eW, const float* __restrict__ c1_ae,
                     const float* __restrict__ c2_eW, const float* __restrict__ c2_ae,
                     float* __restrict__ we1, float* __restrict__ we2) {
    int t = threadIdx.x;
    if (t < 20) {
        int d = t >> 2, h = t & 3;
        float s = 0.f;
        for (int f = 0; f < 16; ++f) s += c1_eW[d * 64 + h * 16 + f] * c1_ae[h * 16 + f];
        we1[d * 4 + h] = s;
    } else if (t >= 32 && t < 37) {
        int d = t - 32;
        float s = 0.f;
        for (int f = 0; f < 32; ++f) s += c2_eW[d * 32 + f] * c2_ae[f];
        we2[d] = s;
    }
}

// ---------------------------------------------------------------------------
// K1: node features -> LayerNorm -> h1 = x @ c1_W, attention scalars as1/ad1.
// One thread per node.
__global__ void __launch_bounds__(256) k_node(
    const float* __restrict__ pol_feat, const int* __restrict__ state_ids,
    const int* __restrict__ sector_ids, const int* __restrict__ industry_ids,
    const float* __restrict__ comp_scalar,
    const float* __restrict__ pol_W, const float* __restrict__ pol_b,
    const float* __restrict__ state_E, const float* __restrict__ sector_E,
    const float* __restrict__ industry_E, const float* __restrict__ comp_W,
    const float* __restrict__ comp_b, const float* __restrict__ comm_E,
    const float* __restrict__ ln_g, const float* __restrict__ ln_b,
    const float* __restrict__ c1_W, const float* __restrict__ c1_as,
    const float* __restrict__ c1_ad,
    float* __restrict__ h1, float* __restrict__ as1, float* __restrict__ ad1) {
    int n = blockIdx.x * blockDim.x + threadIdx.x;
    if (n >= NN) return;
    float x[32];
    if (n < NPOL) {
        float f[7];
        #pragma unroll
        for (int i = 0; i < 7; ++i) f[i] = pol_feat[n * 7 + i];
        int sid = state_ids[n];
        #pragma unroll
        for (int j = 0; j < 32; ++j) {
            float v = pol_b[j];
            #pragma unroll
            for (int i = 0; i < 7; ++i) v += f[i] * pol_W[i * 32 + j];
            v = v > 0.f ? v : 0.f;
            x[j] = v + state_E[sid * 32 + j];
        }
    } else if (n < NPOL + NTICK) {
        int t = n - NPOL;
        float f[17];
        int sec = sector_ids[t], ind = industry_ids[t];
        #pragma unroll
        for (int i = 0; i < 8; ++i) { f[i] = sector_E[sec * 8 + i]; f[8 + i] = industry_E[ind * 8 + i]; }
        f[16] = comp_scalar[t];
        #pragma unroll
        for (int j = 0; j < 32; ++j) {
            float v = comp_b[j];
            #pragma unroll
            for (int i = 0; i < 17; ++i) v += f[i] * comp_W[i * 32 + j];
            x[j] = v > 0.f ? v : 0.f;
        }
    } else {
        int c = n - (NPOL + NTICK);
        #pragma unroll
        for (int j = 0; j < 32; ++j) x[j] = comm_E[c * 32 + j];
    }
    // LayerNorm over 32 dims
    float mu = 0.f;
    #pragma unroll
    for (int j = 0; j < 32; ++j) mu += x[j];
    mu *= (1.f / 32.f);
    float var = 0.f;
    #pragma unroll
    for (int j = 0; j < 32; ++j) { float d = x[j] - mu; var += d * d; }
    var *= (1.f / 32.f);
    float inv = rsqrtf(var + 1e-5f);
    #pragma unroll
    for (int j = 0; j < 32; ++j) x[j] = (x[j] - mu) * inv * ln_g[j] + ln_b[j];
    // h1 = x @ c1_W  (32x64); as1[h] = sum_j h1[j]*c1_as[j] within head h (j = h*16+f)
    #pragma unroll
    for (int h = 0; h < 4; ++h) {
        float av = 0.f, dv = 0.f;
        for (int f = 0; f < 16; ++f) {
            int j = h * 16 + f;
            float v = 0.f;
            #pragma unroll
            for (int i = 0; i < 32; ++i) v += x[i] * c1_W[i * 64 + j];
            h1[n * 64 + j] = v;
            av += v * c1_as[j];
            dv += v * c1_ad[j];
        }
        as1[n * 4 + h] = av;
        ad1[n * 4 + h] = dv;
    }
}

// ---------------------------------------------------------------------------
// K2: in-degree count
__global__ void k_deg(const int* __restrict__ ei, int* __restrict__ deg) {
    int e = blockIdx.x * blockDim.x + threadIdx.x;
    if (e < NE) atomicAdd(&deg[ei[NE + e]], 1);
}

// K3a/b/c: exclusive scan of (deg[n]+1) -> row_start
__global__ void k_scan1(const int* __restrict__ deg, int* __restrict__ row_start,
                        int* __restrict__ bsum) {
    __shared__ int tmp[1024];
    int i = blockIdx.x * 1024 + threadIdx.x;
    int v = (i < NN) ? deg[i] + 1 : 0;
    tmp[threadIdx.x] = v;
    __syncthreads();
    for (int off = 1; off < 1024; off <<= 1) {
        int t = (threadIdx.x >= off) ? tmp[threadIdx.x - off] : 0;
        __syncthreads();
        tmp[threadIdx.x] += t;
        __syncthreads();
    }
    if (i < NN) row_start[i] = tmp[threadIdx.x] - v;
    if (threadIdx.x == 1023) bsum[blockIdx.x] = tmp[1023];
}
__global__ void k_scan2(int* __restrict__ bsum, int nb) {
    __shared__ int tmp[128];
    int t = threadIdx.x;
    int v = (t < nb) ? bsum[t] : 0;
    tmp[t] = v;
    __syncthreads();
    for (int off = 1; off < 128; off <<= 1) {
        int u = (t >= off) ? tmp[t - off] : 0;
        __syncthreads();
        tmp[t] += u;
        __syncthreads();
    }
    if (t < nb) bsum[t] = tmp[t] - v;  // exclusive
}
__global__ void k_scan3(int* __restrict__ row_start, const int* __restrict__ bsum) {
    int i = blockIdx.x * blockDim.x + threadIdx.x;
    if (i < NN) row_start[i] += bsum[i >> 10];
}

// ---------------------------------------------------------------------------
// K4: CSR fill. Slot row_start[d] is reserved for the self-loop; real edges go
// after it. Also precompute per-edge attention terms ae1[pos][4], ae2[pos].
__global__ void k_fill(const int* __restrict__ ei, const float* __restrict__ edge_attr,
                       const int* __restrict__ row_start, int* __restrict__ fill,
                       const float* __restrict__ we1, const float* __restrict__ we2,
                       int* __restrict__ csr_src, float* __restrict__ ae1,
                       float* __restrict__ ae2) {
    int e = blockIdx.x * blockDim.x + threadIdx.x;
    if (e >= NE) return;
    int s = ei[e], d = ei[NE + e];
    int pos = row_start[d] + 1 + atomicAdd(&fill[d], 1);
    csr_src[pos] = s;
    float a[5];
    #pragma unroll
    for (int k = 0; k < 5; ++k) a[k] = edge_attr[e * 5 + k];
    #pragma unroll
    for (int h = 0; h < 4; ++h) {
        float v = 0.f;
        #pragma unroll
        for (int k = 0; k < 5; ++k) v += a[k] * we1[k * 4 + h];
        ae1[pos * 4 + h] = v;
    }
    float v2 = 0.f;
    #pragma unroll
    for (int k = 0; k < 5; ++k) v2 += a[k] * we2[k];
    ae2[pos] = v2;
}

// K5: self-loop entries. loop_attr = mean of incoming edge_attr, and a_edge is
// linear in attr, so a_edge(self) = mean of incoming a_edge.
__global__ void k_self(const int* __restrict__ row_start, const int* __restrict__ deg,
                       int* __restrict__ csr_src, float* __restrict__ ae1,
                       float* __restrict__ ae2) {
    int n = blockIdx.x * blockDim.x + threadIdx.x;
    if (n >= NN) return;
    int base = row_start[n], L = deg[n];
    float s0 = 0.f, s1 = 0.f, s2 = 0.f, s3 = 0.f, s4 = 0.f;
    for (int i = 1; i <= L; ++i) {
        s0 += ae1[(base + i) * 4 + 0];
        s1 += ae1[(base + i) * 4 + 1];
        s2 += ae1[(base + i) * 4 + 2];
        s3 += ae1[(base + i) * 4 + 3];
        s4 += ae2[base + i];
    }
    float inv = 1.f / fmaxf((float)L, 1.f);
    csr_src[base] = n;
    ae1[base * 4 + 0] = s0 * inv;
    ae1[base * 4 + 1] = s1 * inv;
    ae1[base * 4 + 2] = s2 * inv;
    ae1[base * 4 + 3] = s3 * inv;
    ae2[base] = s4 * inv;
}

// ---------------------------------------------------------------------------
// K6: GAT layer 1 aggregation, one wave64 per dst node (lane = out dim, head =
// lane>>4). Two sweeps: max, then exp/sum/accumulate. Fused epilogue: +c1_b,
// ELU, h2 = x1 @ c2_W (via LDS), and layer-2 attention scalars as2/ad2.
__global__ void __launch_bounds__(256) k_agg1(
    const int* __restrict__ row_start, const int* __restrict__ deg,
    const int* __restrict__ csr_src, const float* __restrict__ ae1,
    const float* __restrict__ as1, const float* __restrict__ ad1,
    const float* __restrict__ h1, const float* __restrict__ c1_b,
    const float* __restrict__ c2_W, const float* __restrict__ c2_as,
    const float* __restrict__ c2_ad,
    float* __restrict__ h2, float* __restrict__ as2, float* __restrict__ ad2) {
    __shared__ float lds[4 * 64];
    int wid = threadIdx.x >> 6;
    int lane = threadIdx.x & 63;
    int n = blockIdx.x * 4 + wid;   // grid sized exactly: NN/4 blocks
    int base = row_start[n], len = deg[n] + 1;
    int h = lane >> 4;
    float ad = ad1[n * 4 + h];
    float m = -INFINITY;
    for (int i = 0; i < len; ++i) {
        int s = csr_src[base + i];
        float l = as1[s * 4 + h] + ad + ae1[(base + i) * 4 + h];
        l = (l > 0.f) ? l : 0.2f * l;
        m = fmaxf(m, l);
    }
    float ssum = 0.f, acc = 0.f;
    for (int i = 0; i < len; ++i) {
        int s = csr_src[base + i];
        float l = as1[s * 4 + h] + ad + ae1[(base + i) * 4 + h];
        l = (l > 0.f) ? l : 0.2f * l;
        float ex = __expf(l - m);
        ssum += ex;
        acc += ex * h1[s * 64 + lane];
    }
    float x1 = acc / ssum + c1_b[lane];
    x1 = (x1 > 0.f) ? x1 : (__expf(x1) - 1.f);   // ELU
    lds[wid * 64 + lane] = x1;
    __syncthreads();
    if (lane < 32) {
        float v = 0.f;
        #pragma unroll
        for (int k = 0; k < 64; ++k) v += lds[wid * 64 + k] * c2_W[k * 32 + lane];
        h2[n * 32 + lane] = v;
        float a = v * c2_as[lane], b = v * c2_ad[lane];
        #pragma unroll
        for (int off = 16; off > 0; off >>= 1) {
            a += __shfl_down(a, off, 32);
            b += __shfl_down(b, off, 32);
        }
        if (lane == 0) { as2[n] = a; ad2[n] = b; }
    }
}

// ---------------------------------------------------------------------------
// K7: GAT layer 2 aggregation, one 32-lane group per dst node. Writes d_out.
__global__ void __launch_bounds__(256) k_agg2(
    const int* __restrict__ row_start, const int* __restrict__ deg,
    const int* __restrict__ csr_src, const float* __restrict__ ae2,
    const float* __restrict__ as2, const float* __restrict__ ad2,
    const float* __restrict__ h2, const float* __restrict__ c2_b,
    float* __restrict__ out) {
    int tid = blockIdx.x * blockDim.x + threadIdx.x;
    int n = tid >> 5;
    int l32 = tid & 31;
    if (n >= NN) return;
    int base = row_start[n], len = deg[n] + 1;
    float ad = ad2[n];
    float m = -INFINITY;
    for (int i = 0; i < len; ++i) {
        int s = csr_src[base + i];
        float l = as2[s] + ad + ae2[base + i];
        l = (l > 0.f) ? l : 0.2f * l;
        m = fmaxf(m, l);
    }
    float ssum = 0.f, acc = 0.f;
    for (int i = 0; i < len; ++i) {
        int s = csr_src[base + i];
        float l = as2[s] + ad + ae2[base + i];
        l = (l > 0.f) ? l : 0.2f * l;
        float ex = __expf(l - m);
        ssum += ex;
        acc += ex * h2[s * 32 + l32];
    }
    out[n * 32 + l32] = acc / ssum + c2_b[l32];
}

// ---------------------------------------------------------------------------
extern "C" void kernel_launch(void* const* d_in, const int* in_sizes, int n_in,
                              void* d_out, int out_size, void* d_ws, size_t ws_size,
                              hipStream_t stream) {
    const int*   edge_index  = (const int*)  d_in[0];
    const float* edge_attr   = (const float*)d_in[1];
    const float* pol_feat    = (const float*)d_in[2];
    const int*   state_ids   = (const int*)  d_in[3];
    const int*   sector_ids  = (const int*)  d_in[4];
    const int*   industry_ids= (const int*)  d_in[5];
    const float* comp_scalar = (const float*)d_in[6];
    const float* pol_W   = (const float*)d_in[7];
    const float* pol_b   = (const float*)d_in[8];
    const float* state_E = (const float*)d_in[9];
    const float* sector_E= (const float*)d_in[10];
    const float* industry_E=(const float*)d_in[11];
    const float* comp_W  = (const float*)d_in[12];
    const float* comp_b  = (const float*)d_in[13];
    const float* comm_E  = (const float*)d_in[14];
    const float* ln_g    = (const float*)d_in[15];
    const float* ln_b    = (const float*)d_in[16];
    const float* c1_W    = (const float*)d_in[17];
    const float* c1_as   = (const float*)d_in[18];
    const float* c1_ad   = (const float*)d_in[19];
    const float* c1_eW   = (const float*)d_in[20];
    const float* c1_ae   = (const float*)d_in[21];
    const float* c1_b    = (const float*)d_in[22];
    const float* c2_W    = (const float*)d_in[23];
    const float* c2_as   = (const float*)d_in[24];
    const float* c2_ad   = (const float*)d_in[25];
    const float* c2_eW   = (const float*)d_in[26];
    const float* c2_ae   = (const float*)d_in[27];
    const float* c2_b    = (const float*)d_in[28];
    float* out = (float*)d_out;

    // workspace carve-up (256B aligned)
    char* ws = (char*)d_ws;
    size_t off = 0;
    auto alloc = [&](size_t bytes) { void* p = ws + off; off += (bytes + 255) & ~(size_t)255; return p; };
    int*   deg       = (int*)  alloc(NN * 4);
    int*   fill      = (int*)  alloc(NN * 4);
    int*   row_start = (int*)  alloc(NN * 4);
    int*   bsum      = (int*)  alloc(128 * 4);
    int*   csr_src   = (int*)  alloc((size_t)NE2 * 4);
    float* ae1       = (float*)alloc((size_t)NE2 * 16);
    float* ae2       = (float*)alloc((size_t)NE2 * 4);
    float* h1        = (float*)alloc((size_t)NN * 64 * 4);
    float* as1       = (float*)alloc((size_t)NN * 4 * 4);
    float* ad1       = (float*)alloc((size_t)NN * 4 * 4);
    float* h2        = (float*)alloc((size_t)NN * 32 * 4);
    float* as2       = (float*)alloc(NN * 4);
    float* ad2       = (float*)alloc(NN * 4);
    float* we1       = (float*)alloc(20 * 4);
    float* we2       = (float*)alloc(5 * 4);
    (void)ws_size; (void)in_sizes; (void)n_in; (void)out_size;

    hipMemsetAsync(deg, 0, NN * 4, stream);
    hipMemsetAsync(fill, 0, NN * 4, stream);

    k_we<<<1, 64, 0, stream>>>(c1_eW, c1_ae, c2_eW, c2_ae, we1, we2);
    k_node<<<(NN + 255) / 256, 256, 0, stream>>>(
        pol_feat, state_ids, sector_ids, industry_ids, comp_scalar,
        pol_W, pol_b, state_E, sector_E, industry_E, comp_W, comp_b, comm_E,
        ln_g, ln_b, c1_W, c1_as, c1_ad, h1, as1, ad1);
    k_deg<<<(NE + 255) / 256, 256, 0, stream>>>(edge_index, deg);
    int nblk = (NN + 1023) / 1024;   // 98
    k_scan1<<<nblk, 1024, 0, stream>>>(deg, row_start, bsum);
    k_scan2<<<1, 128, 0, stream>>>(bsum, nblk);
    k_scan3<<<(NN + 255) / 256, 256, 0, stream>>>(row_start, bsum);
    k_fill<<<(NE + 255) / 256, 256, 0, stream>>>(
        edge_index, edge_attr, row_start, fill, we1, we2, csr_src, ae1, ae2);
    k_self<<<(NN + 255) / 256, 256, 0, stream>>>(row_start, deg, csr_src, ae1, ae2);
    k_agg1<<<NN / 4, 256, 0, stream>>>(
        row_start, deg, csr_src, ae1, as1, ad1, h1, c1_b, c2_W, c2_as, c2_ad,
        h2, as2, ad2);
    k_agg2<<<(NN * 32) / 256, 256, 0, stream>>>(
        row_start, deg, csr_src, ae2, as2, ad2, h2, c2_b, out);
}

// Round 2
// 319.674 us; speedup vs baseline: 1.7133x; 1.7133x over previous
//
#include <hip/hip_runtime.h>
#include <math.h>

#define NPOL   1000
#define NTICK  98000
#define NCOMM  1000
#define NN     100000
#define NE     1000000
#define NE2    1100000   // NE + NN self-loops

__device__ __forceinline__ unsigned short f2bf(float v) {
    unsigned u = __float_as_uint(v);
    u += 0x7FFFu + ((u >> 16) & 1u);          // round-to-nearest-even
    return (unsigned short)(u >> 16);
}
__device__ __forceinline__ float bf2f(unsigned short s) {
    return __uint_as_float(((unsigned)s) << 16);
}

// ---------------------------------------------------------------------------
// K0: fold edge-attention weights: we1[d][h] = sum_f c1_eW[d][h*16+f]*c1_ae[h][f]
//     we2[d] = sum_f c2_eW[d][f]*c2_ae[f]
__global__ void k_we(const float* __restrict__ c1_eW, const float* __restrict__ c1_ae,
                     const float* __restrict__ c2_eW, const float* __restrict__ c2_ae,
                     float* __restrict__ we1, float* __restrict__ we2) {
    int t = threadIdx.x;
    if (t < 20) {
        int d = t >> 2, h = t & 3;
        float s = 0.f;
        for (int f = 0; f < 16; ++f) s += c1_eW[d * 64 + h * 16 + f] * c1_ae[h * 16 + f];
        we1[d * 4 + h] = s;
    } else if (t >= 32 && t < 37) {
        int d = t - 32;
        float s = 0.f;
        for (int f = 0; f < 32; ++f) s += c2_eW[d * 32 + f] * c2_ae[f];
        we2[d] = s;
    }
}

// ---------------------------------------------------------------------------
// K1: node features -> LayerNorm -> h1 = x @ c1_W (bf16), scalars as1/ad1 (f32).
__global__ void __launch_bounds__(256) k_node(
    const float* __restrict__ pol_feat, const int* __restrict__ state_ids,
    const int* __restrict__ sector_ids, const int* __restrict__ industry_ids,
    const float* __restrict__ comp_scalar,
    const float* __restrict__ pol_W, const float* __restrict__ pol_b,
    const float* __restrict__ state_E, const float* __restrict__ sector_E,
    const float* __restrict__ industry_E, const float* __restrict__ comp_W,
    const float* __restrict__ comp_b, const float* __restrict__ comm_E,
    const float* __restrict__ ln_g, const float* __restrict__ ln_b,
    const float* __restrict__ c1_W, const float* __restrict__ c1_as,
    const float* __restrict__ c1_ad,
    unsigned short* __restrict__ h1b, float* __restrict__ as1, float* __restrict__ ad1) {
    int n = blockIdx.x * blockDim.x + threadIdx.x;
    if (n >= NN) return;
    float x[32];
    if (n < NPOL) {
        float f[7];
        #pragma unroll
        for (int i = 0; i < 7; ++i) f[i] = pol_feat[n * 7 + i];
        int sid = state_ids[n];
        #pragma unroll
        for (int j = 0; j < 32; ++j) {
            float v = pol_b[j];
            #pragma unroll
            for (int i = 0; i < 7; ++i) v += f[i] * pol_W[i * 32 + j];
            v = v > 0.f ? v : 0.f;
            x[j] = v + state_E[sid * 32 + j];
        }
    } else if (n < NPOL + NTICK) {
        int t = n - NPOL;
        float f[17];
        int sec = sector_ids[t], ind = industry_ids[t];
        #pragma unroll
        for (int i = 0; i < 8; ++i) { f[i] = sector_E[sec * 8 + i]; f[8 + i] = industry_E[ind * 8 + i]; }
        f[16] = comp_scalar[t];
        #pragma unroll
        for (int j = 0; j < 32; ++j) {
            float v = comp_b[j];
            #pragma unroll
            for (int i = 0; i < 17; ++i) v += f[i] * comp_W[i * 32 + j];
            x[j] = v > 0.f ? v : 0.f;
        }
    } else {
        int c = n - (NPOL + NTICK);
        #pragma unroll
        for (int j = 0; j < 32; ++j) x[j] = comm_E[c * 32 + j];
    }
    float mu = 0.f;
    #pragma unroll
    for (int j = 0; j < 32; ++j) mu += x[j];
    mu *= (1.f / 32.f);
    float var = 0.f;
    #pragma unroll
    for (int j = 0; j < 32; ++j) { float d = x[j] - mu; var += d * d; }
    var *= (1.f / 32.f);
    float inv = rsqrtf(var + 1e-5f);
    #pragma unroll
    for (int j = 0; j < 32; ++j) x[j] = (x[j] - mu) * inv * ln_g[j] + ln_b[j];
    #pragma unroll
    for (int h = 0; h < 4; ++h) {
        float av = 0.f, dv = 0.f;
        for (int f = 0; f < 16; ++f) {
            int j = h * 16 + f;
            float v = 0.f;
            #pragma unroll
            for (int i = 0; i < 32; ++i) v += x[i] * c1_W[i * 64 + j];
            h1b[n * 64 + j] = f2bf(v);
            av += v * c1_as[j];
            dv += v * c1_ad[j];
        }
        as1[n * 4 + h] = av;
        ad1[n * 4 + h] = dv;
    }
}

// ---------------------------------------------------------------------------
__global__ void k_deg(const int* __restrict__ ei, int* __restrict__ deg) {
    int e = blockIdx.x * blockDim.x + threadIdx.x;
    if (e < NE) atomicAdd(&deg[ei[NE + e]], 1);
}

__global__ void k_scan1(const int* __restrict__ deg, int* __restrict__ row_start,
                        int* __restrict__ bsum) {
    __shared__ int tmp[1024];
    int i = blockIdx.x * 1024 + threadIdx.x;
    int v = (i < NN) ? deg[i] + 1 : 0;
    tmp[threadIdx.x] = v;
    __syncthreads();
    for (int off = 1; off < 1024; off <<= 1) {
        int t = (threadIdx.x >= off) ? tmp[threadIdx.x - off] : 0;
        __syncthreads();
        tmp[threadIdx.x] += t;
        __syncthreads();
    }
    if (i < NN) row_start[i] = tmp[threadIdx.x] - v;
    if (threadIdx.x == 1023) bsum[blockIdx.x] = tmp[1023];
}
__global__ void k_scan2(int* __restrict__ bsum, int nb) {
    __shared__ int tmp[128];
    int t = threadIdx.x;
    int v = (t < nb) ? bsum[t] : 0;
    tmp[t] = v;
    __syncthreads();
    for (int off = 1; off < 128; off <<= 1) {
        int u = (t >= off) ? tmp[t - off] : 0;
        __syncthreads();
        tmp[t] += u;
        __syncthreads();
    }
    if (t < nb) bsum[t] = tmp[t] - v;
}
__global__ void k_scan3(int* __restrict__ row_start, const int* __restrict__ bsum) {
    int i = blockIdx.x * blockDim.x + threadIdx.x;
    if (i < NN) row_start[i] += bsum[i >> 10];
}

// ---------------------------------------------------------------------------
// K4: CSR fill + per-edge attention terms (slot row_start[d] reserved for self).
__global__ void k_fill(const int* __restrict__ ei, const float* __restrict__ edge_attr,
                       const int* __restrict__ row_start, int* __restrict__ fill,
                       const float* __restrict__ we1, const float* __restrict__ we2,
                       int* __restrict__ csr_src, float* __restrict__ ae1,
                       float* __restrict__ ae2) {
    int e = blockIdx.x * blockDim.x + threadIdx.x;
    if (e >= NE) return;
    int s = ei[e], d = ei[NE + e];
    int pos = row_start[d] + 1 + atomicAdd(&fill[d], 1);
    csr_src[pos] = s;
    float a[5];
    #pragma unroll
    for (int k = 0; k < 5; ++k) a[k] = edge_attr[e * 5 + k];
    #pragma unroll
    for (int h = 0; h < 4; ++h) {
        float v = 0.f;
        #pragma unroll
        for (int k = 0; k < 5; ++k) v += a[k] * we1[k * 4 + h];
        ae1[pos * 4 + h] = v;
    }
    float v2 = 0.f;
    #pragma unroll
    for (int k = 0; k < 5; ++k) v2 += a[k] * we2[k];
    ae2[pos] = v2;
}

// K5: self-loop slots (a_edge of mean attr = mean of a_edge, linearity).
__global__ void k_self(const int* __restrict__ row_start, const int* __restrict__ deg,
                       int* __restrict__ csr_src, float* __restrict__ ae1,
                       float* __restrict__ ae2) {
    int n = blockIdx.x * blockDim.x + threadIdx.x;
    if (n >= NN) return;
    int base = row_start[n], L = deg[n];
    float s0 = 0.f, s1 = 0.f, s2 = 0.f, s3 = 0.f, s4 = 0.f;
    for (int i = 1; i <= L; ++i) {
        s0 += ae1[(base + i) * 4 + 0];
        s1 += ae1[(base + i) * 4 + 1];
        s2 += ae1[(base + i) * 4 + 2];
        s3 += ae1[(base + i) * 4 + 3];
        s4 += ae2[base + i];
    }
    float inv = 1.f / fmaxf((float)L, 1.f);
    csr_src[base] = n;
    ae1[base * 4 + 0] = s0 * inv;
    ae1[base * 4 + 1] = s1 * inv;
    ae1[base * 4 + 2] = s2 * inv;
    ae1[base * 4 + 3] = s3 * inv;
    ae2[base] = s4 * inv;
}

// ---------------------------------------------------------------------------
// K6: GAT layer 1, one wave64 per dst (lane=dim, head=lane>>4). SINGLE pass:
// softmax without max-subtraction (logits bounded, shift-invariant). 2x unroll
// for MLP. Fused epilogue: bias, ELU, h2 = x1@c2_W, layer-2 scalars.
__global__ void __launch_bounds__(256) k_agg1(
    const int* __restrict__ row_start, const int* __restrict__ deg,
    const int* __restrict__ csr_src, const float* __restrict__ ae1,
    const float* __restrict__ as1, const float* __restrict__ ad1,
    const unsigned short* __restrict__ h1b, const float* __restrict__ c1_b,
    const float* __restrict__ c2_W, const float* __restrict__ c2_as,
    const float* __restrict__ c2_ad,
    unsigned short* __restrict__ h2b, float* __restrict__ as2, float* __restrict__ ad2) {
    __shared__ float lds[4 * 64];
    int wid = threadIdx.x >> 6;
    int lane = threadIdx.x & 63;
    int n = blockIdx.x * 4 + wid;
    int base = __builtin_amdgcn_readfirstlane(row_start[n]);
    int len  = __builtin_amdgcn_readfirstlane(deg[n]) + 1;
    int h = lane >> 4;
    float ad = ad1[n * 4 + h];
    float ssum = 0.f, acc = 0.f;
    int i = 0;
    for (; i + 2 <= len; i += 2) {
        int s0 = csr_src[base + i];
        int s1 = csr_src[base + i + 1];
        float e0 = ae1[(base + i) * 4 + h];
        float e1 = ae1[(base + i + 1) * 4 + h];
        float a0 = as1[s0 * 4 + h];
        float a1 = as1[s1 * 4 + h];
        float g0 = bf2f(h1b[s0 * 64 + lane]);
        float g1 = bf2f(h1b[s1 * 64 + lane]);
        float l0 = a0 + ad + e0; l0 = (l0 > 0.f) ? l0 : 0.2f * l0;
        float l1 = a1 + ad + e1; l1 = (l1 > 0.f) ? l1 : 0.2f * l1;
        float x0 = __expf(l0), x1 = __expf(l1);
        ssum += x0 + x1;
        acc += x0 * g0 + x1 * g1;
    }
    if (i < len) {
        int s0 = csr_src[base + i];
        float l0 = as1[s0 * 4 + h] + ad + ae1[(base + i) * 4 + h];
        l0 = (l0 > 0.f) ? l0 : 0.2f * l0;
        float x0 = __expf(l0);
        ssum += x0;
        acc += x0 * bf2f(h1b[s0 * 64 + lane]);
    }
    float x1v = acc / ssum + c1_b[lane];
    x1v = (x1v > 0.f) ? x1v : (__expf(x1v) - 1.f);   // ELU
    lds[wid * 64 + lane] = x1v;
    __syncthreads();
    if (lane < 32) {
        float v = 0.f;
        #pragma unroll
        for (int k = 0; k < 64; ++k) v += lds[wid * 64 + k] * c2_W[k * 32 + lane];
        h2b[n * 32 + lane] = f2bf(v);
        float a = v * c2_as[lane], b = v * c2_ad[lane];
        #pragma unroll
        for (int off = 16; off > 0; off >>= 1) {
            a += __shfl_down(a, off, 32);
            b += __shfl_down(b, off, 32);
        }
        if (lane == 0) { as2[n] = a; ad2[n] = b; }
    }
}

// ---------------------------------------------------------------------------
// K7: GAT layer 2, one 32-lane group per dst, single pass, writes d_out.
__global__ void __launch_bounds__(256) k_agg2(
    const int* __restrict__ row_start, const int* __restrict__ deg,
    const int* __restrict__ csr_src, const float* __restrict__ ae2,
    const float* __restrict__ as2, const float* __restrict__ ad2,
    const unsigned short* __restrict__ h2b, const float* __restrict__ c2_b,
    float* __restrict__ out) {
    int tid = blockIdx.x * blockDim.x + threadIdx.x;
    int n = tid >> 5;
    int l32 = tid & 31;
    if (n >= NN) return;
    int base = row_start[n], len = deg[n] + 1;
    float ad = ad2[n];
    float ssum = 0.f, acc = 0.f;
    int i = 0;
    for (; i + 2 <= len; i += 2) {
        int s0 = csr_src[base + i];
        int s1 = csr_src[base + i + 1];
        float e0 = ae2[base + i];
        float e1 = ae2[base + i + 1];
        float a0 = as2[s0];
        float a1 = as2[s1];
        float g0 = bf2f(h2b[s0 * 32 + l32]);
        float g1 = bf2f(h2b[s1 * 32 + l32]);
        float l0 = a0 + ad + e0; l0 = (l0 > 0.f) ? l0 : 0.2f * l0;
        float l1 = a1 + ad + e1; l1 = (l1 > 0.f) ? l1 : 0.2f * l1;
        float x0 = __expf(l0), x1 = __expf(l1);
        ssum += x0 + x1;
        acc += x0 * g0 + x1 * g1;
    }
    if (i < len) {
        int s0 = csr_src[base + i];
        float l0 = as2[s0] + ad + ae2[base + i];
        l0 = (l0 > 0.f) ? l0 : 0.2f * l0;
        float x0 = __expf(l0);
        ssum += x0;
        acc += x0 * bf2f(h2b[s0 * 32 + l32]);
    }
    out[n * 32 + l32] = acc / ssum + c2_b[l32];
}

// ---------------------------------------------------------------------------
extern "C" void kernel_launch(void* const* d_in, const int* in_sizes, int n_in,
                              void* d_out, int out_size, void* d_ws, size_t ws_size,
                              hipStream_t stream) {
    const int*   edge_index  = (const int*)  d_in[0];
    const float* edge_attr   = (const float*)d_in[1];
    const float* pol_feat    = (const float*)d_in[2];
    const int*   state_ids   = (const int*)  d_in[3];
    const int*   sector_ids  = (const int*)  d_in[4];
    const int*   industry_ids= (const int*)  d_in[5];
    const float* comp_scalar = (const float*)d_in[6];
    const float* pol_W   = (const float*)d_in[7];
    const float* pol_b   = (const float*)d_in[8];
    const float* state_E = (const float*)d_in[9];
    const float* sector_E= (const float*)d_in[10];
    const float* industry_E=(const float*)d_in[11];
    const float* comp_W  = (const float*)d_in[12];
    const float* comp_b  = (const float*)d_in[13];
    const float* comm_E  = (const float*)d_in[14];
    const float* ln_g    = (const float*)d_in[15];
    const float* ln_b    = (const float*)d_in[16];
    const float* c1_W    = (const float*)d_in[17];
    const float* c1_as   = (const float*)d_in[18];
    const float* c1_ad   = (const float*)d_in[19];
    const float* c1_eW   = (const float*)d_in[20];
    const float* c1_ae   = (const float*)d_in[21];
    const float* c1_b    = (const float*)d_in[22];
    const float* c2_W    = (const float*)d_in[23];
    const float* c2_as   = (const float*)d_in[24];
    const float* c2_ad   = (const float*)d_in[25];
    const float* c2_eW   = (const float*)d_in[26];
    const float* c2_ae   = (const float*)d_in[27];
    const float* c2_b    = (const float*)d_in[28];
    float* out = (float*)d_out;

    char* ws = (char*)d_ws;
    size_t off = 0;
    auto alloc = [&](size_t bytes) { void* p = ws + off; off += (bytes + 255) & ~(size_t)255; return p; };
    int*   deg       = (int*)  alloc(NN * 4);
    int*   fill      = (int*)  alloc(NN * 4);
    int*   row_start = (int*)  alloc(NN * 4);
    int*   bsum      = (int*)  alloc(128 * 4);
    int*   csr_src   = (int*)  alloc((size_t)NE2 * 4);
    float* ae1       = (float*)alloc((size_t)NE2 * 16);
    float* ae2       = (float*)alloc((size_t)NE2 * 4);
    unsigned short* h1b = (unsigned short*)alloc((size_t)NN * 64 * 2);
    float* as1       = (float*)alloc((size_t)NN * 4 * 4);
    float* ad1       = (float*)alloc((size_t)NN * 4 * 4);
    unsigned short* h2b = (unsigned short*)alloc((size_t)NN * 32 * 2);
    float* as2       = (float*)alloc(NN * 4);
    float* ad2       = (float*)alloc(NN * 4);
    float* we1       = (float*)alloc(20 * 4);
    float* we2       = (float*)alloc(5 * 4);
    (void)ws_size; (void)in_sizes; (void)n_in; (void)out_size;

    hipMemsetAsync(deg, 0, NN * 4, stream);
    hipMemsetAsync(fill, 0, NN * 4, stream);

    k_we<<<1, 64, 0, stream>>>(c1_eW, c1_ae, c2_eW, c2_ae, we1, we2);
    k_node<<<(NN + 255) / 256, 256, 0, stream>>>(
        pol_feat, state_ids, sector_ids, industry_ids, comp_scalar,
        pol_W, pol_b, state_E, sector_E, industry_E, comp_W, comp_b, comm_E,
        ln_g, ln_b, c1_W, c1_as, c1_ad, h1b, as1, ad1);
    k_deg<<<(NE + 255) / 256, 256, 0, stream>>>(edge_index, deg);
    int nblk = (NN + 1023) / 1024;   // 98
    k_scan1<<<nblk, 1024, 0, stream>>>(deg, row_start, bsum);
    k_scan2<<<1, 128, 0, stream>>>(bsum, nblk);
    k_scan3<<<(NN + 255) / 256, 256, 0, stream>>>(row_start, bsum);
    k_fill<<<(NE + 255) / 256, 256, 0, stream>>>(
        edge_index, edge_attr, row_start, fill, we1, we2, csr_src, ae1, ae2);
    k_self<<<(NN + 255) / 256, 256, 0, stream>>>(row_start, deg, csr_src, ae1, ae2);
    k_agg1<<<NN / 4, 256, 0, stream>>>(
        row_start, deg, csr_src, ae1, as1, ad1, h1b, c1_b, c2_W, c2_as, c2_ad,
        h2b, as2, ad2);
    k_agg2<<<(NN * 32) / 256, 256, 0, stream>>>(
        row_start, deg, csr_src, ae2, as2, ad2, h2b, c2_b, out);
}

// Round 3
// 277.783 us; speedup vs baseline: 1.9717x; 1.1508x over previous
//
#include <hip/hip_runtime.h>
#include <math.h>

#define NPOL   1000
#define NTICK  98000
#define NCOMM  1000
#define NN     100000
#define NE     1000000
#define NE2    1100000   // NE + NN self-loops

__device__ __forceinline__ unsigned short f2bf(float v) {
    unsigned u = __float_as_uint(v);
    u += 0x7FFFu + ((u >> 16) & 1u);          // round-to-nearest-even
    return (unsigned short)(u >> 16);
}
__device__ __forceinline__ float bf2f(unsigned short s) {
    return __uint_as_float(((unsigned)s) << 16);
}

// ---------------------------------------------------------------------------
// K1: node features -> LayerNorm -> h1 = x @ c1_W (bf16), scalars as1/ad1 (f32).
__global__ void __launch_bounds__(256) k_node(
    const float* __restrict__ pol_feat, const int* __restrict__ state_ids,
    const int* __restrict__ sector_ids, const int* __restrict__ industry_ids,
    const float* __restrict__ comp_scalar,
    const float* __restrict__ pol_W, const float* __restrict__ pol_b,
    const float* __restrict__ state_E, const float* __restrict__ sector_E,
    const float* __restrict__ industry_E, const float* __restrict__ comp_W,
    const float* __restrict__ comp_b, const float* __restrict__ comm_E,
    const float* __restrict__ ln_g, const float* __restrict__ ln_b,
    const float* __restrict__ c1_W, const float* __restrict__ c1_as,
    const float* __restrict__ c1_ad,
    unsigned short* __restrict__ h1b, float* __restrict__ as1, float* __restrict__ ad1) {
    int n = blockIdx.x * blockDim.x + threadIdx.x;
    if (n >= NN) return;
    float x[32];
    if (n < NPOL) {
        float f[7];
        #pragma unroll
        for (int i = 0; i < 7; ++i) f[i] = pol_feat[n * 7 + i];
        int sid = state_ids[n];
        #pragma unroll
        for (int j = 0; j < 32; ++j) {
            float v = pol_b[j];
            #pragma unroll
            for (int i = 0; i < 7; ++i) v += f[i] * pol_W[i * 32 + j];
            v = v > 0.f ? v : 0.f;
            x[j] = v + state_E[sid * 32 + j];
        }
    } else if (n < NPOL + NTICK) {
        int t = n - NPOL;
        float f[17];
        int sec = sector_ids[t], ind = industry_ids[t];
        #pragma unroll
        for (int i = 0; i < 8; ++i) { f[i] = sector_E[sec * 8 + i]; f[8 + i] = industry_E[ind * 8 + i]; }
        f[16] = comp_scalar[t];
        #pragma unroll
        for (int j = 0; j < 32; ++j) {
            float v = comp_b[j];
            #pragma unroll
            for (int i = 0; i < 17; ++i) v += f[i] * comp_W[i * 32 + j];
            x[j] = v > 0.f ? v : 0.f;
        }
    } else {
        int c = n - (NPOL + NTICK);
        #pragma unroll
        for (int j = 0; j < 32; ++j) x[j] = comm_E[c * 32 + j];
    }
    float mu = 0.f;
    #pragma unroll
    for (int j = 0; j < 32; ++j) mu += x[j];
    mu *= (1.f / 32.f);
    float var = 0.f;
    #pragma unroll
    for (int j = 0; j < 32; ++j) { float d = x[j] - mu; var += d * d; }
    var *= (1.f / 32.f);
    float inv = rsqrtf(var + 1e-5f);
    #pragma unroll
    for (int j = 0; j < 32; ++j) x[j] = (x[j] - mu) * inv * ln_g[j] + ln_b[j];
    #pragma unroll
    for (int h = 0; h < 4; ++h) {
        float av = 0.f, dv = 0.f;
        for (int f = 0; f < 16; ++f) {
            int j = h * 16 + f;
            float v = 0.f;
            #pragma unroll
            for (int i = 0; i < 32; ++i) v += x[i] * c1_W[i * 64 + j];
            h1b[n * 64 + j] = f2bf(v);
            av += v * c1_as[j];
            dv += v * c1_ad[j];
        }
        as1[n * 4 + h] = av;
        ad1[n * 4 + h] = dv;
    }
}

// ---------------------------------------------------------------------------
__global__ void k_deg(const int* __restrict__ ei, int* __restrict__ deg) {
    int e = blockIdx.x * blockDim.x + threadIdx.x;
    if (e < NE) atomicAdd(&deg[ei[NE + e]], 1);
}

__global__ void k_scan1(const int* __restrict__ deg, int* __restrict__ row_start,
                        int* __restrict__ bsum) {
    __shared__ int tmp[1024];
    int i = blockIdx.x * 1024 + threadIdx.x;
    int v = (i < NN) ? deg[i] + 1 : 0;
    tmp[threadIdx.x] = v;
    __syncthreads();
    for (int off = 1; off < 1024; off <<= 1) {
        int t = (threadIdx.x >= off) ? tmp[threadIdx.x - off] : 0;
        __syncthreads();
        tmp[threadIdx.x] += t;
        __syncthreads();
    }
    if (i < NN) row_start[i] = tmp[threadIdx.x] - v;
    if (threadIdx.x == 1023) bsum[blockIdx.x] = tmp[1023];
}
__global__ void k_scan2(int* __restrict__ bsum, int nb) {
    __shared__ int tmp[128];
    int t = threadIdx.x;
    int v = (t < nb) ? bsum[t] : 0;
    tmp[t] = v;
    __syncthreads();
    for (int off = 1; off < 128; off <<= 1) {
        int u = (t >= off) ? tmp[t - off] : 0;
        __syncthreads();
        tmp[t] += u;
        __syncthreads();
    }
    if (t < nb) bsum[t] = tmp[t] - v;
}
__global__ void k_scan3(int* __restrict__ row_start, const int* __restrict__ bsum) {
    int i = blockIdx.x * blockDim.x + threadIdx.x;
    if (i < NN) row_start[i] += bsum[i >> 10];
}

// ---------------------------------------------------------------------------
// K4: CSR fill into packed 32B records {src, ae1[4], ae2, pad2}. Slot
// row_start[d] reserved for the self-loop (written later by k_agg1).
// Edge-attention weight folding (k_we) is computed per-block in LDS.
__global__ void __launch_bounds__(256) k_fill(
    const int* __restrict__ ei, const float* __restrict__ edge_attr,
    const int* __restrict__ row_start, int* __restrict__ fill,
    const float* __restrict__ c1_eW, const float* __restrict__ c1_ae,
    const float* __restrict__ c2_eW, const float* __restrict__ c2_ae,
    float* __restrict__ rec) {
    __shared__ float we1s[20];
    __shared__ float we2s[5];
    int t = threadIdx.x;
    if (t < 20) {
        int d = t >> 2, h = t & 3;
        float s = 0.f;
        for (int f = 0; f < 16; ++f) s += c1_eW[d * 64 + h * 16 + f] * c1_ae[h * 16 + f];
        we1s[t] = s;
    } else if (t >= 32 && t < 37) {
        int d = t - 32;
        float s = 0.f;
        for (int f = 0; f < 32; ++f) s += c2_eW[d * 32 + f] * c2_ae[f];
        we2s[d] = s;
    }
    __syncthreads();
    int e = blockIdx.x * blockDim.x + t;
    if (e >= NE) return;
    int s = ei[e], d = ei[NE + e];
    int pos = row_start[d] + 1 + atomicAdd(&fill[d], 1);
    float a[5];
    #pragma unroll
    for (int k = 0; k < 5; ++k) a[k] = edge_attr[e * 5 + k];
    float e0 = 0.f, e1 = 0.f, e2 = 0.f, e3 = 0.f, e4 = 0.f;
    #pragma unroll
    for (int k = 0; k < 5; ++k) {
        e0 += a[k] * we1s[k * 4 + 0];
        e1 += a[k] * we1s[k * 4 + 1];
        e2 += a[k] * we1s[k * 4 + 2];
        e3 += a[k] * we1s[k * 4 + 3];
        e4 += a[k] * we2s[k];
    }
    float4* rp = (float4*)rec;
    rp[(size_t)pos * 2]     = make_float4(__int_as_float(s), e0, e1, e2);
    rp[(size_t)pos * 2 + 1] = make_float4(e3, e4, 0.f, 0.f);
}

// ---------------------------------------------------------------------------
// K6: GAT layer 1, one wave64 per dst. Two-phase per 64-edge chunk:
//  A: lane i loads record i (coalesced 32B), gathers as1[src] (L2-resident),
//     computes p[4 heads] = exp(leaky(logit)) lane-parallel, deposits in LDS.
//     Also accumulates ae-sums for the self-loop (reduced at the end).
//  B: walk the chunk; per edge only ONE random gather (h1b), 4-deep unrolled.
// Fused epilogue: bias, ELU, h2 = x1@c2_W, layer-2 scalars, self record slot.
__global__ void __launch_bounds__(256) k_agg1(
    const int* __restrict__ row_start, const int* __restrict__ deg,
    float* __restrict__ rec,
    const float* __restrict__ as1, const float* __restrict__ ad1,
    const unsigned short* __restrict__ h1b, const float* __restrict__ c1_b,
    const float* __restrict__ c2_W, const float* __restrict__ c2_as,
    const float* __restrict__ c2_ad,
    unsigned short* __restrict__ h2b, float* __restrict__ as2, float* __restrict__ ad2) {
    __shared__ float pT[4][64][4];
    __shared__ int   srcT[4][64];
    __shared__ float xT[4][64];
    int wid = threadIdx.x >> 6;
    int lane = threadIdx.x & 63;
    int h = lane >> 4;
    int n = blockIdx.x * 4 + wid;
    int base = __builtin_amdgcn_readfirstlane(row_start[n]);
    int dg   = __builtin_amdgcn_readfirstlane(deg[n]);
    const float4* as1v4 = (const float4*)as1;
    const float4* ad1v4 = (const float4*)ad1;
    float4 adv = ad1v4[n];
    float4 asv_self = as1v4[n];
    float gself = bf2f(h1b[(size_t)n * 64 + lane]);
    const float4* rp = (const float4*)rec;

    float ssum = 0.f, acc = 0.f;
    float aes0 = 0.f, aes1 = 0.f, aes2 = 0.f, aes3 = 0.f, ae2sum = 0.f;

    for (int i0 = 0; i0 < dg; i0 += 64) {
        int clen = dg - i0; if (clen > 64) clen = 64;
        int idx = i0 + lane;
        if (idx < dg) {
            size_t p0 = (size_t)(base + 1 + idx) * 2;
            float4 r0 = rp[p0];
            float4 r1 = rp[p0 + 1];
            int s = __float_as_int(r0.x);
            float4 av = as1v4[s];
            float l0 = av.x + adv.x + r0.y; l0 = l0 > 0.f ? l0 : 0.2f * l0;
            float l1 = av.y + adv.y + r0.z; l1 = l1 > 0.f ? l1 : 0.2f * l1;
            float l2 = av.z + adv.z + r0.w; l2 = l2 > 0.f ? l2 : 0.2f * l2;
            float l3 = av.w + adv.w + r1.x; l3 = l3 > 0.f ? l3 : 0.2f * l3;
            float4 q = make_float4(__expf(l0), __expf(l1), __expf(l2), __expf(l3));
            *(float4*)&pT[wid][lane][0] = q;
            srcT[wid][lane] = s;
            aes0 += r0.y; aes1 += r0.z; aes2 += r0.w; aes3 += r1.x;
            ae2sum += r1.y;
        }
        int i = 0;
        for (; i + 4 <= clen; i += 4) {
            int s0 = srcT[wid][i],     s1 = srcT[wid][i + 1];
            int s2 = srcT[wid][i + 2], s3 = srcT[wid][i + 3];
            float q0 = pT[wid][i][h],     q1 = pT[wid][i + 1][h];
            float q2 = pT[wid][i + 2][h], q3 = pT[wid][i + 3][h];
            float g0 = bf2f(h1b[(size_t)s0 * 64 + lane]);
            float g1 = bf2f(h1b[(size_t)s1 * 64 + lane]);
            float g2 = bf2f(h1b[(size_t)s2 * 64 + lane]);
            float g3 = bf2f(h1b[(size_t)s3 * 64 + lane]);
            ssum += (q0 + q1) + (q2 + q3);
            acc = fmaf(q0, g0, fmaf(q1, g1, fmaf(q2, g2, fmaf(q3, g3, acc))));
        }
        for (; i < clen; ++i) {
            int s0 = srcT[wid][i];
            float q0 = pT[wid][i][h];
            float g0 = bf2f(h1b[(size_t)s0 * 64 + lane]);
            ssum += q0;
            acc = fmaf(q0, g0, acc);
        }
    }
    // cross-lane reduce the self-loop ae sums
    #pragma unroll
    for (int m = 1; m < 64; m <<= 1) {
        aes0 += __shfl_xor(aes0, m);
        aes1 += __shfl_xor(aes1, m);
        aes2 += __shfl_xor(aes2, m);
        aes3 += __shfl_xor(aes3, m);
        ae2sum += __shfl_xor(ae2sum, m);
    }
    float invd = 1.f / fmaxf((float)dg, 1.f);
    float aesh = (h == 0) ? aes0 : (h == 1) ? aes1 : (h == 2) ? aes2 : aes3;
    float adh  = (h == 0) ? adv.x : (h == 1) ? adv.y : (h == 2) ? adv.z : adv.w;
    float ash  = (h == 0) ? asv_self.x : (h == 1) ? asv_self.y : (h == 2) ? asv_self.z : asv_self.w;
    float ls = ash + adh + aesh * invd;
    ls = ls > 0.f ? ls : 0.2f * ls;
    float ps = __expf(ls);
    ssum += ps;
    acc = fmaf(ps, gself, acc);
    // write the self-loop record slot for layer 2
    if (lane == 0) {
        ((int*)rec)[(size_t)base * 8] = n;
        rec[(size_t)base * 8 + 5] = ae2sum * invd;
    }
    float x1v = acc / ssum + c1_b[lane];
    x1v = (x1v > 0.f) ? x1v : (__expf(x1v) - 1.f);   // ELU
    xT[wid][lane] = x1v;
    __syncthreads();
    if (lane < 32) {
        float v = 0.f;
        #pragma unroll
        for (int k = 0; k < 64; ++k) v += xT[wid][k] * c2_W[k * 32 + lane];
        h2b[n * 32 + lane] = f2bf(v);
        float a = v * c2_as[lane], b = v * c2_ad[lane];
        #pragma unroll
        for (int off = 16; off > 0; off >>= 1) {
            a += __shfl_down(a, off, 32);
            b += __shfl_down(b, off, 32);
        }
        if (lane == 0) { as2[n] = a; ad2[n] = b; }
    }
}

// ---------------------------------------------------------------------------
// K7: GAT layer 2, one 32-lane group per dst, same two-phase structure.
// Row includes the self slot at position 0 (written by k_agg1).
__global__ void __launch_bounds__(256) k_agg2(
    const int* __restrict__ row_start, const int* __restrict__ deg,
    const float* __restrict__ rec, const float* __restrict__ as2,
    const float* __restrict__ ad2, const unsigned short* __restrict__ h2b,
    const float* __restrict__ c2_b, float* __restrict__ out) {
    __shared__ float2 spT[8][32];
    int t = threadIdx.x;
    int half = t >> 5;
    int l32 = t & 31;
    int n = blockIdx.x * 8 + half;
    int base = row_start[n];
    int len = deg[n] + 1;
    float ad2n = ad2[n];
    float ssum = 0.f, acc = 0.f;
    for (int i0 = 0; i0 < len; i0 += 32) {
        int clen = len - i0; if (clen > 32) clen = 32;
        int idx = i0 + l32;
        float p = 0.f; int s = 0;
        if (idx < len) {
            size_t b8 = (size_t)(base + idx) * 8;
            s = ((const int*)rec)[b8];
            float ae2v = rec[b8 + 5];
            float l = as2[s] + ad2n + ae2v;
            l = l > 0.f ? l : 0.2f * l;
            p = __expf(l);
        }
        ssum += p;
        spT[half][l32] = make_float2(__int_as_float(s), p);
        int i = 0;
        for (; i + 4 <= clen; i += 4) {
            float2 e0 = spT[half][i],     e1 = spT[half][i + 1];
            float2 e2 = spT[half][i + 2], e3 = spT[half][i + 3];
            int s0 = __float_as_int(e0.x), s1 = __float_as_int(e1.x);
            int s2 = __float_as_int(e2.x), s3 = __float_as_int(e3.x);
            float g0 = bf2f(h2b[(size_t)s0 * 32 + l32]);
            float g1 = bf2f(h2b[(size_t)s1 * 32 + l32]);
            float g2 = bf2f(h2b[(size_t)s2 * 32 + l32]);
            float g3 = bf2f(h2b[(size_t)s3 * 32 + l32]);
            acc = fmaf(e0.y, g0, fmaf(e1.y, g1, fmaf(e2.y, g2, fmaf(e3.y, g3, acc))));
        }
        for (; i < clen; ++i) {
            float2 e0 = spT[half][i];
            int s0 = __float_as_int(e0.x);
            acc = fmaf(e0.y, bf2f(h2b[(size_t)s0 * 32 + l32]), acc);
        }
    }
    #pragma unroll
    for (int m = 1; m < 32; m <<= 1) ssum += __shfl_xor(ssum, m, 32);
    out[(size_t)n * 32 + l32] = acc / ssum + c2_b[l32];
}

// ---------------------------------------------------------------------------
extern "C" void kernel_launch(void* const* d_in, const int* in_sizes, int n_in,
                              void* d_out, int out_size, void* d_ws, size_t ws_size,
                              hipStream_t stream) {
    const int*   edge_index  = (const int*)  d_in[0];
    const float* edge_attr   = (const float*)d_in[1];
    const float* pol_feat    = (const float*)d_in[2];
    const int*   state_ids   = (const int*)  d_in[3];
    const int*   sector_ids  = (const int*)  d_in[4];
    const int*   industry_ids= (const int*)  d_in[5];
    const float* comp_scalar = (const float*)d_in[6];
    const float* pol_W   = (const float*)d_in[7];
    const float* pol_b   = (const float*)d_in[8];
    const float* state_E = (const float*)d_in[9];
    const float* sector_E= (const float*)d_in[10];
    const float* industry_E=(const float*)d_in[11];
    const float* comp_W  = (const float*)d_in[12];
    const float* comp_b  = (const float*)d_in[13];
    const float* comm_E  = (const float*)d_in[14];
    const float* ln_g    = (const float*)d_in[15];
    const float* ln_b    = (const float*)d_in[16];
    const float* c1_W    = (const float*)d_in[17];
    const float* c1_as   = (const float*)d_in[18];
    const float* c1_ad   = (const float*)d_in[19];
    const float* c1_eW   = (const float*)d_in[20];
    const float* c1_ae   = (const float*)d_in[21];
    const float* c1_b    = (const float*)d_in[22];
    const float* c2_W    = (const float*)d_in[23];
    const float* c2_as   = (const float*)d_in[24];
    const float* c2_ad   = (const float*)d_in[25];
    const float* c2_eW   = (const float*)d_in[26];
    const float* c2_ae   = (const float*)d_in[27];
    const float* c2_b    = (const float*)d_in[28];
    float* out = (float*)d_out;

    char* ws = (char*)d_ws;
    size_t off = 0;
    auto alloc = [&](size_t bytes) { void* p = ws + off; off += (bytes + 255) & ~(size_t)255; return p; };
    int*   deg       = (int*)  alloc(NN * 4);
    int*   fill      = (int*)  alloc(NN * 4);
    int*   row_start = (int*)  alloc(NN * 4);
    int*   bsum      = (int*)  alloc(128 * 4);
    float* rec       = (float*)alloc((size_t)NE2 * 32);
    unsigned short* h1b = (unsigned short*)alloc((size_t)NN * 64 * 2);
    float* as1       = (float*)alloc((size_t)NN * 4 * 4);
    float* ad1       = (float*)alloc((size_t)NN * 4 * 4);
    unsigned short* h2b = (unsigned short*)alloc((size_t)NN * 32 * 2);
    float* as2       = (float*)alloc(NN * 4);
    float* ad2       = (float*)alloc(NN * 4);
    (void)ws_size; (void)in_sizes; (void)n_in; (void)out_size;

    hipMemsetAsync(deg, 0, NN * 4, stream);
    hipMemsetAsync(fill, 0, NN * 4, stream);

    k_node<<<(NN + 255) / 256, 256, 0, stream>>>(
        pol_feat, state_ids, sector_ids, industry_ids, comp_scalar,
        pol_W, pol_b, state_E, sector_E, industry_E, comp_W, comp_b, comm_E,
        ln_g, ln_b, c1_W, c1_as, c1_ad, h1b, as1, ad1);
    k_deg<<<(NE + 255) / 256, 256, 0, stream>>>(edge_index, deg);
    int nblk = (NN + 1023) / 1024;   // 98
    k_scan1<<<nblk, 1024, 0, stream>>>(deg, row_start, bsum);
    k_scan2<<<1, 128, 0, stream>>>(bsum, nblk);
    k_scan3<<<(NN + 255) / 256, 256, 0, stream>>>(row_start, bsum);
    k_fill<<<(NE + 255) / 256, 256, 0, stream>>>(
        edge_index, edge_attr, row_start, fill, c1_eW, c1_ae, c2_eW, c2_ae, rec);
    k_agg1<<<NN / 4, 256, 0, stream>>>(
        row_start, deg, rec, as1, ad1, h1b, c1_b, c2_W, c2_as, c2_ad,
        h2b, as2, ad2);
    k_agg2<<<NN / 8, 256, 0, stream>>>(
        row_start, deg, rec, as2, ad2, h2b, c2_b, out);
}